// Round 7
// baseline (596.207 us; speedup 1.0000x reference)
//
#include <hip/hip_runtime.h>
#include <hip/hip_bf16.h>

#define NN 2000
#define EE 32000
#define TT 12
#define CIN 32
#define FCH 64
#define TB 96
#define NODE_F 3072    // TB*CIN elements per scrambled node
#define NODE_U 1536    // packed bf16 pairs (uints) per node

// workspace layout (32-bit word offsets)
#define OFF_X0B   0            // uint[2000*1536]
#define OFF_TX1B  3072000      // uint[2000*1536]
#define OFF_CHEB  6144000      // ushort[2000*6144] bf16 cheb
#define OFF_DEG   18432000
#define OFF_SW    18434000
#define OFF_ROWP  18436000     // int[2048]
#define OFF_CNT   18438048     // int[2000]
#define OFF_FILL  18440048     // int[2000]
#define OFF_CCOL  18442048     // int[32000]
#define OFF_CW    18474048     // float[32000]
#define OFF_TWT   18506048     // ushort[12288] bf16 time_w [fc*3+j][ft]
#define OFF_RWT   18512192     // ushort[2048]  bf16 res_w  [c][ft]

__device__ __forceinline__ float comp4(const float4& v, int i) {
  return i == 0 ? v.x : (i == 1 ? v.y : (i == 2 ? v.z : v.w));
}
__device__ __forceinline__ float b2f(unsigned short u) {
  return __uint_as_float(((unsigned)u) << 16);
}
__device__ __forceinline__ unsigned short f2b(float x) {
  __hip_bfloat16 h = __float2bfloat16(x);   // RNE
  return *(unsigned short*)&h;
}
__device__ __forceinline__ float lo2f(unsigned u) { return __uint_as_float(u << 16); }
__device__ __forceinline__ float hi2f(unsigned u) { return __uint_as_float(u & 0xffff0000u); }
__device__ __forceinline__ unsigned pack2(float a, float b) {
  return (unsigned)f2b(a) | ((unsigned)f2b(b) << 16);
}

// ---- 0. pre-transpose conv weights to bf16 (once, tiny) ----
__global__ __launch_bounds__(256) void k_prep(const float* __restrict__ tw,
    const float* __restrict__ rw, unsigned short* __restrict__ twt,
    unsigned short* __restrict__ rwt) {
  int i = blockIdx.x * 256 + threadIdx.x;
  if (i < 12288) {
    int ft = i / 192;
    int r = i - ft * 192;
    twt[r * 64 + ft] = f2b(tw[i]);
  }
  if (i < 2048) {
    int ft = i >> 5;
    int c = i & 31;
    rwt[c * 64 + ft] = f2b(rw[i]);
  }
}

// ---- 1. degree (by src) and in-count (by dst) ----
__global__ __launch_bounds__(256) void k_deg_cnt(const int* __restrict__ src,
    const int* __restrict__ dst, const float* __restrict__ ew,
    float* __restrict__ deg, int* __restrict__ cnt) {
  int e = blockIdx.x * 256 + threadIdx.x;
  if (e < EE) {
    atomicAdd(&deg[src[e]], ew[e]);
    atomicAdd(&cnt[dst[e]], 1);
  }
}

// ---- 2. self-loop weights + exclusive scan of cnt -> rowptr ----
__global__ __launch_bounds__(256) void k_scan(const float* __restrict__ deg,
    const float* __restrict__ lam, const int* __restrict__ cnt,
    float* __restrict__ sw, int* __restrict__ rowp) {
  int tid = threadIdx.x;
  float s = 2.0f / lam[0];
  for (int n = tid; n < NN; n += 256) sw[n] = deg[n] * s - 1.0f;
  __shared__ int part[256];
  int base = tid * 8;
  int local[8];
  int sum = 0;
  #pragma unroll
  for (int i = 0; i < 8; ++i) {
    int idx = base + i;
    int v = (idx < NN) ? cnt[idx] : 0;
    local[i] = sum;
    sum += v;
  }
  part[tid] = sum;
  __syncthreads();
  for (int off = 1; off < 256; off <<= 1) {
    int v = part[tid];
    int add = (tid >= off) ? part[tid - off] : 0;
    __syncthreads();
    part[tid] = v + add;
    __syncthreads();
  }
  int excl = part[tid] - sum;  // exclusive prefix of this chunk
  #pragma unroll
  for (int i = 0; i < 8; ++i) {
    int idx = base + i;
    if (idx < NN) rowp[idx] = excl + local[i];
  }
  if (tid == 255) rowp[NN] = part[255];
}

// ---- 3. CSR fill (rows = dst). w_e = -2*ew/lam - [src==dst] ----
__global__ __launch_bounds__(256) void k_fill(const int* __restrict__ src,
    const int* __restrict__ dst, const float* __restrict__ ew,
    const float* __restrict__ lam, const int* __restrict__ rowp,
    int* __restrict__ fill, int* __restrict__ ccol, float* __restrict__ cw) {
  int e = blockIdx.x * 256 + threadIdx.x;
  if (e < EE) {
    float s = 2.0f / lam[0];
    int d = dst[e], sn = src[e];
    int pos = rowp[d] + atomicAdd(&fill[d], 1);
    ccol[pos] = sn;
    cw[pos] = -ew[e] * s - ((sn == d) ? 1.0f : 0.0f);
  }
}

// ---- 4. build scrambled x0 (bf16 packed), coalesced 12-float runs ----
__global__ __launch_bounds__(256) void k_build_x0(const float* __restrict__ X,
                                                  unsigned* __restrict__ x0b) {
  __shared__ float lds[32 * 97 + 32];
  int n = blockIdx.x, r = threadIdx.x;
  int G = n * NODE_F + r * 12;
  int ci = G / 192000;            // C stride = B*N*T
  int r1 = G - ci * 192000;
  int b = r1 / 24000;             // N*T
  int nn2 = (r1 - b * 24000) / 12;
  const float4* sp = (const float4*)(X + (((size_t)(b * NN + nn2) * CIN + ci) * TT));
  float4 v0 = sp[0], v1 = sp[1], v2 = sp[2];
  int c2 = r >> 3;
  int qb = (r & 7) * 12;
  float* d = &lds[c2 * 97 + qb];
  d[0]=v0.x; d[1]=v0.y; d[2]=v0.z; d[3]=v0.w;
  d[4]=v1.x; d[5]=v1.y; d[6]=v1.z; d[7]=v1.w;
  d[8]=v2.x; d[9]=v2.y; d[10]=v2.z; d[11]=v2.w;
  __syncthreads();
  unsigned* op = x0b + (size_t)n * NODE_U;
  #pragma unroll
  for (int k = 0; k < 6; ++k) {
    int i2 = r + k * 256;
    int o0 = 2 * i2, o1 = 2 * i2 + 1;
    float a0 = lds[(o0 & 31) * 97 + (o0 >> 5)];
    float a1 = lds[(o1 & 31) * 97 + (o1 >> 5)];
    op[i2] = pack2(a0, a1);
  }
}

// ---- 5. Tx1 = L_hat @ x0 (block per node, 12 elems/thread, bf16 in/out) ----
__global__ __launch_bounds__(256, 4) void k_prop1(const unsigned* __restrict__ x0b,
    const float* __restrict__ sw, const int* __restrict__ rowp,
    const int* __restrict__ ccol, const float* __restrict__ cw,
    unsigned* __restrict__ tx1b) {
  int n = blockIdx.x, tid = threadIdx.x;
  float s = sw[n];
  float a[12];
  {
    const uint2* p = (const uint2*)(x0b + (size_t)n * NODE_U + tid * 6);
    uint2 u0 = p[0], u1 = p[1], u2 = p[2];
    a[0]=s*lo2f(u0.x); a[1]=s*hi2f(u0.x); a[2]=s*lo2f(u0.y); a[3]=s*hi2f(u0.y);
    a[4]=s*lo2f(u1.x); a[5]=s*hi2f(u1.x); a[6]=s*lo2f(u1.y); a[7]=s*hi2f(u1.y);
    a[8]=s*lo2f(u2.x); a[9]=s*hi2f(u2.x); a[10]=s*lo2f(u2.y); a[11]=s*hi2f(u2.y);
  }
  int rs = rowp[n], re = rowp[n + 1];
  for (int e = rs; e < re; ++e) {
    int c = ccol[e];
    float w = cw[e];
    const uint2* p = (const uint2*)(x0b + (size_t)c * NODE_U + tid * 6);
    uint2 u0 = p[0], u1 = p[1], u2 = p[2];
    a[0]+=w*lo2f(u0.x); a[1]+=w*hi2f(u0.x); a[2]+=w*lo2f(u0.y); a[3]+=w*hi2f(u0.y);
    a[4]+=w*lo2f(u1.x); a[5]+=w*hi2f(u1.x); a[6]+=w*lo2f(u1.y); a[7]+=w*hi2f(u1.y);
    a[8]+=w*lo2f(u2.x); a[9]+=w*hi2f(u2.x); a[10]+=w*lo2f(u2.y); a[11]+=w*hi2f(u2.y);
  }
  uint2* ob = (uint2*)(tx1b + (size_t)n * NODE_U + tid * 6);
  ob[0] = make_uint2(pack2(a[0], a[1]), pack2(a[2], a[3]));
  ob[1] = make_uint2(pack2(a[4], a[5]), pack2(a[6], a[7]));
  ob[2] = make_uint2(pack2(a[8], a[9]), pack2(a[10], a[11]));
}

// ---- 6. Tx2 = 2*L_hat@Tx1 - x0 ; cheb = relu(x0@W0 + Tx1@W1 + Tx2@W2 + b) ----
// Register-bounded: einsum split in two q-halves with o[12]; forced <=128 VGPR.
// cheb written as bf16 (u16 stores, wave-contiguous 128 B).
__global__ __launch_bounds__(256, 4) void k_cheb(const unsigned* __restrict__ x0b,
    const unsigned* __restrict__ tx1b, const float* __restrict__ sw,
    const int* __restrict__ rowp, const int* __restrict__ ccol,
    const float* __restrict__ cw, const float* __restrict__ Wc,
    const float* __restrict__ bc, unsigned short* __restrict__ chebb) {
  __shared__ __align__(16) unsigned x0l[NODE_U];   // 6 KB bf16 pairs
  __shared__ __align__(16) unsigned t1l[NODE_U];   // 6 KB
  __shared__ __align__(16) unsigned t2l[NODE_U];   // 6 KB
  __shared__ __align__(16) unsigned short wl[3 * 2048];  // 12 KB bf16 weights
  __shared__ float bl[64];
  int n = blockIdx.x, tid = threadIdx.x;
  {
    const uint4* xs = (const uint4*)(x0b + (size_t)n * NODE_U);
    const uint4* ts = (const uint4*)(tx1b + (size_t)n * NODE_U);
    uint4* xd = (uint4*)x0l;
    uint4* td = (uint4*)t1l;
    for (int i = tid; i < NODE_U / 4; i += 256) { xd[i] = xs[i]; td[i] = ts[i]; }
    for (int i = tid; i < 6144; i += 256) wl[i] = f2b(Wc[i]);
    if (tid < 64) bl[tid] = bc[tid];
  }
  // a = L_hat @ Tx1 on own 12 elements (global reads; LDS not needed yet)
  float s = sw[n];
  float a[12];
  {
    const uint2* p = (const uint2*)(tx1b + (size_t)n * NODE_U + tid * 6);
    uint2 u0 = p[0], u1 = p[1], u2 = p[2];
    a[0]=s*lo2f(u0.x); a[1]=s*hi2f(u0.x); a[2]=s*lo2f(u0.y); a[3]=s*hi2f(u0.y);
    a[4]=s*lo2f(u1.x); a[5]=s*hi2f(u1.x); a[6]=s*lo2f(u1.y); a[7]=s*hi2f(u1.y);
    a[8]=s*lo2f(u2.x); a[9]=s*hi2f(u2.x); a[10]=s*lo2f(u2.y); a[11]=s*hi2f(u2.y);
  }
  int rs = rowp[n], re = rowp[n + 1];
  for (int e = rs; e < re; ++e) {
    int c = ccol[e];
    float w = cw[e];
    const uint2* p = (const uint2*)(tx1b + (size_t)c * NODE_U + tid * 6);
    uint2 u0 = p[0], u1 = p[1], u2 = p[2];
    a[0]+=w*lo2f(u0.x); a[1]+=w*hi2f(u0.x); a[2]+=w*lo2f(u0.y); a[3]+=w*hi2f(u0.y);
    a[4]+=w*lo2f(u1.x); a[5]+=w*hi2f(u1.x); a[6]+=w*lo2f(u1.y); a[7]+=w*hi2f(u1.y);
    a[8]+=w*lo2f(u2.x); a[9]+=w*hi2f(u2.x); a[10]+=w*lo2f(u2.y); a[11]+=w*hi2f(u2.y);
  }
  __syncthreads();   // staging complete; x0l readable, t2l writable
  // t2 = 2a - x0 on own 6 packed words
  #pragma unroll
  for (int k = 0; k < 6; ++k) {
    unsigned ux = x0l[tid * 6 + k];
    t2l[tid * 6 + k] = pack2(2.0f * a[2 * k] - lo2f(ux),
                             2.0f * a[2 * k + 1] - hi2f(ux));
  }
  __syncthreads();
  // einsum in two q-halves; thread (qg = tid>>6, f = tid&63)
  int f = tid & 63, qg = tid >> 6;
  unsigned short* cp = chebb + (size_t)n * TB * FCH;
  for (int half = 0; half < 2; ++half) {
    float o[12];
    #pragma unroll
    for (int qi = 0; qi < 12; ++qi) o[qi] = bl[f];
    for (int cc = 0; cc < 4; ++cc) {
      float w0r[8], w1r[8], w2r[8];
      #pragma unroll
      for (int i = 0; i < 8; ++i) {
        int c = cc * 8 + i;
        w0r[i] = b2f(wl[c * 64 + f]);
        w1r[i] = b2f(wl[2048 + c * 64 + f]);
        w2r[i] = b2f(wl[4096 + c * 64 + f]);
      }
      #pragma unroll 4
      for (int qi = 0; qi < 12; ++qi) {
        int q = (half * 12 + qi) * 4 + qg;
        uint4 ux = *(const uint4*)(&x0l[q * 16 + cc * 4]);   // 8 bf16, wave-uniform
        uint4 uy = *(const uint4*)(&t1l[q * 16 + cc * 4]);
        uint4 uz = *(const uint4*)(&t2l[q * 16 + cc * 4]);
        float acc = o[qi];
        acc += lo2f(ux.x)*w0r[0] + hi2f(ux.x)*w0r[1] + lo2f(ux.y)*w0r[2] + hi2f(ux.y)*w0r[3]
             + lo2f(ux.z)*w0r[4] + hi2f(ux.z)*w0r[5] + lo2f(ux.w)*w0r[6] + hi2f(ux.w)*w0r[7];
        acc += lo2f(uy.x)*w1r[0] + hi2f(uy.x)*w1r[1] + lo2f(uy.y)*w1r[2] + hi2f(uy.y)*w1r[3]
             + lo2f(uy.z)*w1r[4] + hi2f(uy.z)*w1r[5] + lo2f(uy.w)*w1r[6] + hi2f(uy.w)*w1r[7];
        acc += lo2f(uz.x)*w2r[0] + hi2f(uz.x)*w2r[1] + lo2f(uz.y)*w2r[2] + hi2f(uz.y)*w2r[3]
             + lo2f(uz.z)*w2r[4] + hi2f(uz.z)*w2r[5] + lo2f(uz.w)*w2r[6] + hi2f(uz.w)*w2r[7];
        o[qi] = acc;
      }
    }
    #pragma unroll
    for (int qi = 0; qi < 12; ++qi) {
      int q = (half * 12 + qi) * 4 + qg;
      cp[q * 64 + f] = f2b(fmaxf(o[qi], 0.0f));
    }
  }
}

// ---- 7. temporal conv + residual + relu + layernorm(F) + output transpose ----
// Block = 4 waves on ONE (b,n) pair; 8 sequential pairs/block. Weights in
// VGPRs; cheb read as bf16 via wave-uniform (scalar-path) loads, unpack on
// the scalar pipe. Partials reduced via LDS.
__global__ __launch_bounds__(256, 4) void k_final3(const float* __restrict__ X,
    const unsigned short* __restrict__ chebb, const unsigned short* __restrict__ twt,
    const unsigned short* __restrict__ rwt, const float* __restrict__ tb,
    const float* __restrict__ rb, const float* __restrict__ lg,
    const float* __restrict__ lb, float* __restrict__ out) {
  __shared__ float hp[4 * 12 * 64];   // partial h per wave
  __shared__ float zb[64 * 13];       // normalized z, [f][13] padded
  int tid = threadIdx.x;
  int f = tid & 63;
  int ntu = __builtin_amdgcn_readfirstlane(tid >> 6);  // wave id, provably uniform

  // per-lane weights in VGPRs (loaded once; coalesced over f)
  float w0[16], w1[16], w2[16];
  #pragma unroll
  for (int i = 0; i < 16; ++i) {
    int fc = ntu * 16 + i;
    w0[i] = b2f(twt[(fc * 3 + 0) * 64 + f]);
    w1[i] = b2f(twt[(fc * 3 + 1) * 64 + f]);
    w2[i] = b2f(twt[(fc * 3 + 2) * 64 + f]);
  }
  float rwv[8];
  #pragma unroll
  for (int i = 0; i < 8; ++i) rwv[i] = b2f(rwt[(ntu * 8 + i) * 64 + f]);
  float tbf = tb[f], rbf = rb[f], lgf = lg[f], lbf = lb[f];
  float hbase = (ntu == 0) ? (tbf + rbf) : 0.0f;

  for (int it = 0; it < 8; ++it) {
    int p = blockIdx.x * 8 + it;      // uniform pair index = b*2000 + n
    int b = p / 2000;
    int n = p - b * 2000;
    float h[12];
    #pragma unroll
    for (int t = 0; t < 12; ++t) h[t] = hbase;
    // temporal conv partial over this wave's 16 fc (uniform bf16 reads)
    {
      const unsigned short* chp = chebb + (size_t)n * 6144 + b * 768 + ntu * 16;
      #pragma unroll
      for (int r = 0; r < 12; ++r) {
        uint4 ua = *(const uint4*)(chp + r * 64);
        uint4 ub = *(const uint4*)(chp + r * 64 + 8);
        #pragma unroll
        for (int i = 0; i < 16; ++i) {
          unsigned uw = (i < 8) ? ((const unsigned*)&ua)[i >> 1]
                                : ((const unsigned*)&ub)[(i - 8) >> 1];
          float v = (i & 1) ? hi2f(uw) : lo2f(uw);
          if (r <= 10) h[r + 1] += w0[i] * v;
          h[r] += w1[i] * v;
          if (r >= 1) h[r - 1] += w2[i] * v;
        }
      }
    }
    // residual partial over this wave's 8 channels (scalar-path reads)
    {
      const float4* xp4 = (const float4*)(X + (size_t)p * 384 + ntu * 96);
      #pragma unroll
      for (int ci = 0; ci < 24; ++ci) {
        float4 xv = xp4[ci];
        #pragma unroll
        for (int k = 0; k < 4; ++k) {
          int idx = ci * 4 + k;            // 0..95, static
          h[idx % 12] += rwv[idx / 12] * comp4(xv, k);
        }
      }
    }
    // write partials, reduce, LN
    #pragma unroll
    for (int t = 0; t < 12; ++t) hp[ntu * 768 + t * 64 + f] = h[t];
    __syncthreads();
    #pragma unroll
    for (int tt = 0; tt < 3; ++tt) {
      int t = ntu * 3 + tt;
      float v = hp[t * 64 + f] + hp[768 + t * 64 + f]
              + hp[1536 + t * 64 + f] + hp[2304 + t * 64 + f];
      v = fmaxf(v, 0.0f);
      float sum = v, sq = v * v;
      #pragma unroll
      for (int off = 32; off; off >>= 1) {
        sum += __shfl_xor(sum, off);
        sq += __shfl_xor(sq, off);
      }
      float mu = sum * (1.0f / 64.0f);
      float var = sq * (1.0f / 64.0f) - mu * mu;
      float inv = rsqrtf(var + 1e-5f);
      zb[f * 13 + t] = (v - mu) * inv * lgf + lbf;
    }
    __syncthreads();
    // coalesced store: out[p][f][t] = 768 consecutive floats
    float* op = out + (size_t)p * 768;
    #pragma unroll
    for (int k = 0; k < 3; ++k) {
      int i = tid + k * 256;
      op[i] = zb[(i / 12) * 13 + i % 12];
    }
  }
}

extern "C" void kernel_launch(void* const* d_in, const int* in_sizes, int n_in,
                              void* d_out, int out_size, void* d_ws, size_t ws_size,
                              hipStream_t stream) {
  const float* X   = (const float*)d_in[0];
  const int*   ei  = (const int*)d_in[1];
  const float* ew  = (const float*)d_in[2];
  const float* lam = (const float*)d_in[3];
  const float* Wc  = (const float*)d_in[4];
  const float* bc  = (const float*)d_in[5];
  const float* tw  = (const float*)d_in[6];
  const float* tb  = (const float*)d_in[7];
  const float* rw  = (const float*)d_in[8];
  const float* rb  = (const float*)d_in[9];
  const float* lg  = (const float*)d_in[10];
  const float* lb  = (const float*)d_in[11];
  float* out = (float*)d_out;
  float* ws = (float*)d_ws;
  unsigned* x0b  = (unsigned*)(ws + OFF_X0B);
  unsigned* tx1b = (unsigned*)(ws + OFF_TX1B);
  unsigned short* chebb = (unsigned short*)(ws + OFF_CHEB);
  float* deg  = ws + OFF_DEG;
  float* swv  = ws + OFF_SW;
  int* rowp = (int*)(ws + OFF_ROWP);
  int* cnt  = (int*)(ws + OFF_CNT);
  int* fill = (int*)(ws + OFF_FILL);
  int* ccol = (int*)(ws + OFF_CCOL);
  float* cwv = ws + OFF_CW;
  unsigned short* twt = (unsigned short*)(ws + OFF_TWT);
  unsigned short* rwt = (unsigned short*)(ws + OFF_RWT);
  const int* srcp = ei;
  const int* dstp = ei + EE;

  hipMemsetAsync(deg, 0, (size_t)(OFF_CCOL - OFF_DEG) * sizeof(float), stream);
  k_prep<<<48, 256, 0, stream>>>(tw, rw, twt, rwt);
  k_deg_cnt<<<(EE + 255) / 256, 256, 0, stream>>>(srcp, dstp, ew, deg, cnt);
  k_scan<<<1, 256, 0, stream>>>(deg, lam, cnt, swv, rowp);
  k_fill<<<(EE + 255) / 256, 256, 0, stream>>>(srcp, dstp, ew, lam, rowp, fill, ccol, cwv);
  k_build_x0<<<NN, 256, 0, stream>>>(X, x0b);
  k_prop1<<<NN, 256, 0, stream>>>(x0b, swv, rowp, ccol, cwv, tx1b);
  k_cheb<<<NN, 256, 0, stream>>>(x0b, tx1b, swv, rowp, ccol, cwv, Wc, bc, chebb);
  k_final3<<<2000, 256, 0, stream>>>(X, chebb, twt, rwt, tb, rb, lg, lb, out);
}

// Round 8
// 464.111 us; speedup vs baseline: 1.2846x; 1.2846x over previous
//
#include <hip/hip_runtime.h>
#include <hip/hip_bf16.h>

#define NN 2000
#define EE 32000
#define TT 12
#define CIN 32
#define FCH 64
#define TB 96
#define NODE_F 3072    // TB*CIN elements per scrambled node
#define NODE_U 1536    // packed bf16 pairs (uints) per node

// workspace layout (32-bit word offsets)
#define OFF_X0B   0            // uint[2000*1536]
#define OFF_TX1B  3072000      // uint[2000*1536]
#define OFF_CHEB  6144000      // ushort[2000*6144] bf16 cheb
#define OFF_DEG   18432000
#define OFF_SW    18434000
#define OFF_ROWP  18436000     // int[2048]
#define OFF_CNT   18438048     // int[2000]
#define OFF_FILL  18440048     // int[2000]
#define OFF_CCOL  18442048     // int[32000]
#define OFF_CW    18474048     // float[32000]
#define OFF_TWT   18506048     // ushort[12288] bf16 time_w [fc*3+j][ft]
#define OFF_RWT   18512192     // ushort[2048]  bf16 res_w  [c][ft]

__device__ __forceinline__ float comp4(const float4& v, int i) {
  return i == 0 ? v.x : (i == 1 ? v.y : (i == 2 ? v.z : v.w));
}
__device__ __forceinline__ float b2f(unsigned short u) {
  return __uint_as_float(((unsigned)u) << 16);
}
__device__ __forceinline__ unsigned short f2b(float x) {
  __hip_bfloat16 h = __float2bfloat16(x);   // RNE
  return *(unsigned short*)&h;
}
__device__ __forceinline__ float lo2f(unsigned u) { return __uint_as_float(u << 16); }
__device__ __forceinline__ float hi2f(unsigned u) { return __uint_as_float(u & 0xffff0000u); }
__device__ __forceinline__ unsigned pack2(float a, float b) {
  return (unsigned)f2b(a) | ((unsigned)f2b(b) << 16);
}

// ---- 0. pre-transpose conv weights to bf16 (once, tiny) ----
__global__ __launch_bounds__(256) void k_prep(const float* __restrict__ tw,
    const float* __restrict__ rw, unsigned short* __restrict__ twt,
    unsigned short* __restrict__ rwt) {
  int i = blockIdx.x * 256 + threadIdx.x;
  if (i < 12288) {
    int ft = i / 192;
    int r = i - ft * 192;
    twt[r * 64 + ft] = f2b(tw[i]);
  }
  if (i < 2048) {
    int ft = i >> 5;
    int c = i & 31;
    rwt[c * 64 + ft] = f2b(rw[i]);
  }
}

// ---- 1. degree (by src) and in-count (by dst) ----
__global__ __launch_bounds__(256) void k_deg_cnt(const int* __restrict__ src,
    const int* __restrict__ dst, const float* __restrict__ ew,
    float* __restrict__ deg, int* __restrict__ cnt) {
  int e = blockIdx.x * 256 + threadIdx.x;
  if (e < EE) {
    atomicAdd(&deg[src[e]], ew[e]);
    atomicAdd(&cnt[dst[e]], 1);
  }
}

// ---- 2. self-loop weights + exclusive scan of cnt -> rowptr ----
__global__ __launch_bounds__(256) void k_scan(const float* __restrict__ deg,
    const float* __restrict__ lam, const int* __restrict__ cnt,
    float* __restrict__ sw, int* __restrict__ rowp) {
  int tid = threadIdx.x;
  float s = 2.0f / lam[0];
  for (int n = tid; n < NN; n += 256) sw[n] = deg[n] * s - 1.0f;
  __shared__ int part[256];
  int base = tid * 8;
  int local[8];
  int sum = 0;
  #pragma unroll
  for (int i = 0; i < 8; ++i) {
    int idx = base + i;
    int v = (idx < NN) ? cnt[idx] : 0;
    local[i] = sum;
    sum += v;
  }
  part[tid] = sum;
  __syncthreads();
  for (int off = 1; off < 256; off <<= 1) {
    int v = part[tid];
    int add = (tid >= off) ? part[tid - off] : 0;
    __syncthreads();
    part[tid] = v + add;
    __syncthreads();
  }
  int excl = part[tid] - sum;  // exclusive prefix of this chunk
  #pragma unroll
  for (int i = 0; i < 8; ++i) {
    int idx = base + i;
    if (idx < NN) rowp[idx] = excl + local[i];
  }
  if (tid == 255) rowp[NN] = part[255];
}

// ---- 3. CSR fill (rows = dst). w_e = -2*ew/lam - [src==dst] ----
__global__ __launch_bounds__(256) void k_fill(const int* __restrict__ src,
    const int* __restrict__ dst, const float* __restrict__ ew,
    const float* __restrict__ lam, const int* __restrict__ rowp,
    int* __restrict__ fill, int* __restrict__ ccol, float* __restrict__ cw) {
  int e = blockIdx.x * 256 + threadIdx.x;
  if (e < EE) {
    float s = 2.0f / lam[0];
    int d = dst[e], sn = src[e];
    int pos = rowp[d] + atomicAdd(&fill[d], 1);
    ccol[pos] = sn;
    cw[pos] = -ew[e] * s - ((sn == d) ? 1.0f : 0.0f);
  }
}

// ---- 4. build scrambled x0 (bf16 packed), coalesced 12-float runs ----
__global__ __launch_bounds__(256) void k_build_x0(const float* __restrict__ X,
                                                  unsigned* __restrict__ x0b) {
  __shared__ float lds[32 * 97 + 32];
  int n = blockIdx.x, r = threadIdx.x;
  int G = n * NODE_F + r * 12;
  int ci = G / 192000;            // C stride = B*N*T
  int r1 = G - ci * 192000;
  int b = r1 / 24000;             // N*T
  int nn2 = (r1 - b * 24000) / 12;
  const float4* sp = (const float4*)(X + (((size_t)(b * NN + nn2) * CIN + ci) * TT));
  float4 v0 = sp[0], v1 = sp[1], v2 = sp[2];
  int c2 = r >> 3;
  int qb = (r & 7) * 12;
  float* d = &lds[c2 * 97 + qb];
  d[0]=v0.x; d[1]=v0.y; d[2]=v0.z; d[3]=v0.w;
  d[4]=v1.x; d[5]=v1.y; d[6]=v1.z; d[7]=v1.w;
  d[8]=v2.x; d[9]=v2.y; d[10]=v2.z; d[11]=v2.w;
  __syncthreads();
  unsigned* op = x0b + (size_t)n * NODE_U;
  #pragma unroll
  for (int k = 0; k < 6; ++k) {
    int i2 = r + k * 256;
    int o0 = 2 * i2, o1 = 2 * i2 + 1;
    float a0 = lds[(o0 & 31) * 97 + (o0 >> 5)];
    float a1 = lds[(o1 & 31) * 97 + (o1 >> 5)];
    op[i2] = pack2(a0, a1);
  }
}

// ---- 5. Tx1 = L_hat @ x0 ----
// Ownership: thread t owns words {4t..4t+3} U {1024+2t,+1} (elements
// {8t..8t+7} U {2048+4t..+3}) so every load/store is wave-contiguous
// dwordx4/dwordx2 with full cache-line utilization.
__global__ __launch_bounds__(256, 4) void k_prop1(const unsigned* __restrict__ x0b,
    const float* __restrict__ sw, const int* __restrict__ rowp,
    const int* __restrict__ ccol, const float* __restrict__ cw,
    unsigned* __restrict__ tx1b) {
  int n = blockIdx.x, tid = threadIdx.x;
  float s = sw[n];
  float a[12];
  {
    const unsigned* base = x0b + (size_t)n * NODE_U;
    uint4 u = *(const uint4*)(base + tid * 4);
    uint2 v = *(const uint2*)(base + 1024 + tid * 2);
    a[0]=s*lo2f(u.x); a[1]=s*hi2f(u.x); a[2]=s*lo2f(u.y); a[3]=s*hi2f(u.y);
    a[4]=s*lo2f(u.z); a[5]=s*hi2f(u.z); a[6]=s*lo2f(u.w); a[7]=s*hi2f(u.w);
    a[8]=s*lo2f(v.x); a[9]=s*hi2f(v.x); a[10]=s*lo2f(v.y); a[11]=s*hi2f(v.y);
  }
  int rs = rowp[n], re = rowp[n + 1];
  for (int e = rs; e < re; ++e) {
    int c = ccol[e];
    float w = cw[e];
    const unsigned* base = x0b + (size_t)c * NODE_U;
    uint4 u = *(const uint4*)(base + tid * 4);
    uint2 v = *(const uint2*)(base + 1024 + tid * 2);
    a[0]+=w*lo2f(u.x); a[1]+=w*hi2f(u.x); a[2]+=w*lo2f(u.y); a[3]+=w*hi2f(u.y);
    a[4]+=w*lo2f(u.z); a[5]+=w*hi2f(u.z); a[6]+=w*lo2f(u.w); a[7]+=w*hi2f(u.w);
    a[8]+=w*lo2f(v.x); a[9]+=w*hi2f(v.x); a[10]+=w*lo2f(v.y); a[11]+=w*hi2f(v.y);
  }
  unsigned* ob = tx1b + (size_t)n * NODE_U;
  *(uint4*)(ob + tid * 4) = make_uint4(pack2(a[0], a[1]), pack2(a[2], a[3]),
                                       pack2(a[4], a[5]), pack2(a[6], a[7]));
  *(uint2*)(ob + 1024 + tid * 2) = make_uint2(pack2(a[8], a[9]), pack2(a[10], a[11]));
}

// ---- 6. Tx2 = 2*L_hat@Tx1 - x0 ; cheb = relu(x0@W0 + Tx1@W1 + Tx2@W2 + b) ----
// Same coalesced ownership for gathers; output staged through LDS (chl) and
// stored with cooperative uint4 bursts (sub-dword global stores don't merge).
__global__ __launch_bounds__(256, 4) void k_cheb(const unsigned* __restrict__ x0b,
    const unsigned* __restrict__ tx1b, const float* __restrict__ sw,
    const int* __restrict__ rowp, const int* __restrict__ ccol,
    const float* __restrict__ cw, const float* __restrict__ Wc,
    const float* __restrict__ bc, unsigned short* __restrict__ chebb) {
  __shared__ __align__(16) unsigned x0l[NODE_U];   // 6 KB bf16 pairs
  __shared__ __align__(16) unsigned t1l[NODE_U];   // 6 KB
  __shared__ __align__(16) unsigned t2l[NODE_U];   // 6 KB
  __shared__ __align__(16) unsigned chl[3072];     // 12 KB packed bf16 output
  __shared__ __align__(16) unsigned short wl[3 * 2048];  // 12 KB bf16 weights
  __shared__ float bl[64];
  int n = blockIdx.x, tid = threadIdx.x;
  {
    const uint4* xs = (const uint4*)(x0b + (size_t)n * NODE_U);
    const uint4* ts = (const uint4*)(tx1b + (size_t)n * NODE_U);
    uint4* xd = (uint4*)x0l;
    uint4* td = (uint4*)t1l;
    for (int i = tid; i < NODE_U / 4; i += 256) { xd[i] = xs[i]; td[i] = ts[i]; }
    for (int i = tid; i < 6144; i += 256) wl[i] = f2b(Wc[i]);
    if (tid < 64) bl[tid] = bc[tid];
  }
  // a = L_hat @ Tx1 on own 12 elements (global reads; LDS not needed yet)
  float s = sw[n];
  float a[12];
  {
    const unsigned* base = tx1b + (size_t)n * NODE_U;
    uint4 u = *(const uint4*)(base + tid * 4);
    uint2 v = *(const uint2*)(base + 1024 + tid * 2);
    a[0]=s*lo2f(u.x); a[1]=s*hi2f(u.x); a[2]=s*lo2f(u.y); a[3]=s*hi2f(u.y);
    a[4]=s*lo2f(u.z); a[5]=s*hi2f(u.z); a[6]=s*lo2f(u.w); a[7]=s*hi2f(u.w);
    a[8]=s*lo2f(v.x); a[9]=s*hi2f(v.x); a[10]=s*lo2f(v.y); a[11]=s*hi2f(v.y);
  }
  int rs = rowp[n], re = rowp[n + 1];
  for (int e = rs; e < re; ++e) {
    int c = ccol[e];
    float w = cw[e];
    const unsigned* base = tx1b + (size_t)c * NODE_U;
    uint4 u = *(const uint4*)(base + tid * 4);
    uint2 v = *(const uint2*)(base + 1024 + tid * 2);
    a[0]+=w*lo2f(u.x); a[1]+=w*hi2f(u.x); a[2]+=w*lo2f(u.y); a[3]+=w*hi2f(u.y);
    a[4]+=w*lo2f(u.z); a[5]+=w*hi2f(u.z); a[6]+=w*lo2f(u.w); a[7]+=w*hi2f(u.w);
    a[8]+=w*lo2f(v.x); a[9]+=w*hi2f(v.x); a[10]+=w*lo2f(v.y); a[11]+=w*hi2f(v.y);
  }
  __syncthreads();   // staging complete; x0l readable, t2l writable
  // t2 = 2a - x0 on own words
  #pragma unroll
  for (int k = 0; k < 4; ++k) {
    unsigned ux = x0l[tid * 4 + k];
    t2l[tid * 4 + k] = pack2(2.0f * a[2 * k] - lo2f(ux),
                             2.0f * a[2 * k + 1] - hi2f(ux));
  }
  #pragma unroll
  for (int k = 0; k < 2; ++k) {
    unsigned ux = x0l[1024 + tid * 2 + k];
    t2l[1024 + tid * 2 + k] = pack2(2.0f * a[8 + 2 * k] - lo2f(ux),
                                    2.0f * a[9 + 2 * k] - hi2f(ux));
  }
  __syncthreads();
  // einsum in two q-halves; thread (qg = tid>>6, f = tid&63)
  int f = tid & 63, qg = tid >> 6;
  unsigned short* chl16 = (unsigned short*)chl;
  for (int half = 0; half < 2; ++half) {
    float o[12];
    #pragma unroll
    for (int qi = 0; qi < 12; ++qi) o[qi] = bl[f];
    for (int cc = 0; cc < 4; ++cc) {
      float w0r[8], w1r[8], w2r[8];
      #pragma unroll
      for (int i = 0; i < 8; ++i) {
        int c = cc * 8 + i;
        w0r[i] = b2f(wl[c * 64 + f]);
        w1r[i] = b2f(wl[2048 + c * 64 + f]);
        w2r[i] = b2f(wl[4096 + c * 64 + f]);
      }
      #pragma unroll 4
      for (int qi = 0; qi < 12; ++qi) {
        int q = (half * 12 + qi) * 4 + qg;
        uint4 ux = *(const uint4*)(&x0l[q * 16 + cc * 4]);   // 8 bf16, wave-uniform
        uint4 uy = *(const uint4*)(&t1l[q * 16 + cc * 4]);
        uint4 uz = *(const uint4*)(&t2l[q * 16 + cc * 4]);
        float acc = o[qi];
        acc += lo2f(ux.x)*w0r[0] + hi2f(ux.x)*w0r[1] + lo2f(ux.y)*w0r[2] + hi2f(ux.y)*w0r[3]
             + lo2f(ux.z)*w0r[4] + hi2f(ux.z)*w0r[5] + lo2f(ux.w)*w0r[6] + hi2f(ux.w)*w0r[7];
        acc += lo2f(uy.x)*w1r[0] + hi2f(uy.x)*w1r[1] + lo2f(uy.y)*w1r[2] + hi2f(uy.y)*w1r[3]
             + lo2f(uy.z)*w1r[4] + hi2f(uy.z)*w1r[5] + lo2f(uy.w)*w1r[6] + hi2f(uy.w)*w1r[7];
        acc += lo2f(uz.x)*w2r[0] + hi2f(uz.x)*w2r[1] + lo2f(uz.y)*w2r[2] + hi2f(uz.y)*w2r[3]
             + lo2f(uz.z)*w2r[4] + hi2f(uz.z)*w2r[5] + lo2f(uz.w)*w2r[6] + hi2f(uz.w)*w2r[7];
        o[qi] = acc;
      }
    }
    #pragma unroll
    for (int qi = 0; qi < 12; ++qi) {
      int q = (half * 12 + qi) * 4 + qg;
      chl16[q * 64 + f] = f2b(fmaxf(o[qi], 0.0f));   // LDS u16 write, 2-way free
    }
  }
  __syncthreads();
  // cooperative burst store: 768 uint4 = 12 KB, wave-contiguous 1 KB/instr
  {
    uint4* cp4 = (uint4*)(chebb + (size_t)n * TB * FCH);
    const uint4* cl4 = (const uint4*)chl;
    #pragma unroll
    for (int k = 0; k < 3; ++k) cp4[tid + k * 256] = cl4[tid + k * 256];
  }
}

// ---- 7. temporal conv + residual + relu + layernorm(F) + output transpose ----
// Block = 4 waves on ONE (b,n) pair; 8 sequential pairs/block. Weights in
// VGPRs; cheb read as bf16 via wave-uniform (scalar-path) loads, unpack on
// the scalar pipe. Partials reduced via LDS.
__global__ __launch_bounds__(256, 4) void k_final3(const float* __restrict__ X,
    const unsigned short* __restrict__ chebb, const unsigned short* __restrict__ twt,
    const unsigned short* __restrict__ rwt, const float* __restrict__ tb,
    const float* __restrict__ rb, const float* __restrict__ lg,
    const float* __restrict__ lb, float* __restrict__ out) {
  __shared__ float hp[4 * 12 * 64];   // partial h per wave
  __shared__ float zb[64 * 13];       // normalized z, [f][13] padded
  int tid = threadIdx.x;
  int f = tid & 63;
  int ntu = __builtin_amdgcn_readfirstlane(tid >> 6);  // wave id, provably uniform

  // per-lane weights in VGPRs (loaded once; coalesced over f)
  float w0[16], w1[16], w2[16];
  #pragma unroll
  for (int i = 0; i < 16; ++i) {
    int fc = ntu * 16 + i;
    w0[i] = b2f(twt[(fc * 3 + 0) * 64 + f]);
    w1[i] = b2f(twt[(fc * 3 + 1) * 64 + f]);
    w2[i] = b2f(twt[(fc * 3 + 2) * 64 + f]);
  }
  float rwv[8];
  #pragma unroll
  for (int i = 0; i < 8; ++i) rwv[i] = b2f(rwt[(ntu * 8 + i) * 64 + f]);
  float tbf = tb[f], rbf = rb[f], lgf = lg[f], lbf = lb[f];
  float hbase = (ntu == 0) ? (tbf + rbf) : 0.0f;

  for (int it = 0; it < 8; ++it) {
    int p = blockIdx.x * 8 + it;      // uniform pair index = b*2000 + n
    int b = p / 2000;
    int n = p - b * 2000;
    float h[12];
    #pragma unroll
    for (int t = 0; t < 12; ++t) h[t] = hbase;
    // temporal conv partial over this wave's 16 fc (uniform bf16 reads)
    {
      const unsigned short* chp = chebb + (size_t)n * 6144 + b * 768 + ntu * 16;
      #pragma unroll
      for (int r = 0; r < 12; ++r) {
        uint4 ua = *(const uint4*)(chp + r * 64);
        uint4 ub = *(const uint4*)(chp + r * 64 + 8);
        #pragma unroll
        for (int i = 0; i < 16; ++i) {
          unsigned uw = (i < 8) ? ((const unsigned*)&ua)[i >> 1]
                                : ((const unsigned*)&ub)[(i - 8) >> 1];
          float v = (i & 1) ? hi2f(uw) : lo2f(uw);
          if (r <= 10) h[r + 1] += w0[i] * v;
          h[r] += w1[i] * v;
          if (r >= 1) h[r - 1] += w2[i] * v;
        }
      }
    }
    // residual partial over this wave's 8 channels (scalar-path reads)
    {
      const float4* xp4 = (const float4*)(X + (size_t)p * 384 + ntu * 96);
      #pragma unroll
      for (int ci = 0; ci < 24; ++ci) {
        float4 xv = xp4[ci];
        #pragma unroll
        for (int k = 0; k < 4; ++k) {
          int idx = ci * 4 + k;            // 0..95, static
          h[idx % 12] += rwv[idx / 12] * comp4(xv, k);
        }
      }
    }
    // write partials, reduce, LN
    #pragma unroll
    for (int t = 0; t < 12; ++t) hp[ntu * 768 + t * 64 + f] = h[t];
    __syncthreads();
    #pragma unroll
    for (int tt = 0; tt < 3; ++tt) {
      int t = ntu * 3 + tt;
      float v = hp[t * 64 + f] + hp[768 + t * 64 + f]
              + hp[1536 + t * 64 + f] + hp[2304 + t * 64 + f];
      v = fmaxf(v, 0.0f);
      float sum = v, sq = v * v;
      #pragma unroll
      for (int off = 32; off; off >>= 1) {
        sum += __shfl_xor(sum, off);
        sq += __shfl_xor(sq, off);
      }
      float mu = sum * (1.0f / 64.0f);
      float var = sq * (1.0f / 64.0f) - mu * mu;
      float inv = rsqrtf(var + 1e-5f);
      zb[f * 13 + t] = (v - mu) * inv * lgf + lbf;
    }
    __syncthreads();
    // coalesced store: out[p][f][t] = 768 consecutive floats
    float* op = out + (size_t)p * 768;
    #pragma unroll
    for (int k = 0; k < 3; ++k) {
      int i = tid + k * 256;
      op[i] = zb[(i / 12) * 13 + i % 12];
    }
  }
}

extern "C" void kernel_launch(void* const* d_in, const int* in_sizes, int n_in,
                              void* d_out, int out_size, void* d_ws, size_t ws_size,
                              hipStream_t stream) {
  const float* X   = (const float*)d_in[0];
  const int*   ei  = (const int*)d_in[1];
  const float* ew  = (const float*)d_in[2];
  const float* lam = (const float*)d_in[3];
  const float* Wc  = (const float*)d_in[4];
  const float* bc  = (const float*)d_in[5];
  const float* tw  = (const float*)d_in[6];
  const float* tb  = (const float*)d_in[7];
  const float* rw  = (const float*)d_in[8];
  const float* rb  = (const float*)d_in[9];
  const float* lg  = (const float*)d_in[10];
  const float* lb  = (const float*)d_in[11];
  float* out = (float*)d_out;
  float* ws = (float*)d_ws;
  unsigned* x0b  = (unsigned*)(ws + OFF_X0B);
  unsigned* tx1b = (unsigned*)(ws + OFF_TX1B);
  unsigned short* chebb = (unsigned short*)(ws + OFF_CHEB);
  float* deg  = ws + OFF_DEG;
  float* swv  = ws + OFF_SW;
  int* rowp = (int*)(ws + OFF_ROWP);
  int* cnt  = (int*)(ws + OFF_CNT);
  int* fill = (int*)(ws + OFF_FILL);
  int* ccol = (int*)(ws + OFF_CCOL);
  float* cwv = ws + OFF_CW;
  unsigned short* twt = (unsigned short*)(ws + OFF_TWT);
  unsigned short* rwt = (unsigned short*)(ws + OFF_RWT);
  const int* srcp = ei;
  const int* dstp = ei + EE;

  hipMemsetAsync(deg, 0, (size_t)(OFF_CCOL - OFF_DEG) * sizeof(float), stream);
  k_prep<<<48, 256, 0, stream>>>(tw, rw, twt, rwt);
  k_deg_cnt<<<(EE + 255) / 256, 256, 0, stream>>>(srcp, dstp, ew, deg, cnt);
  k_scan<<<1, 256, 0, stream>>>(deg, lam, cnt, swv, rowp);
  k_fill<<<(EE + 255) / 256, 256, 0, stream>>>(srcp, dstp, ew, lam, rowp, fill, ccol, cwv);
  k_build_x0<<<NN, 256, 0, stream>>>(X, x0b);
  k_prop1<<<NN, 256, 0, stream>>>(x0b, swv, rowp, ccol, cwv, tx1b);
  k_cheb<<<NN, 256, 0, stream>>>(x0b, tx1b, swv, rowp, ccol, cwv, Wc, bc, chebb);
  k_final3<<<2000, 256, 0, stream>>>(X, chebb, twt, rwt, tb, rb, lg, lb, out);
}